// Round 8
// baseline (53.587 us; speedup 1.0000x reference)
//
#include <hip/hip_runtime.h>
#include <hip/hip_bf16.h>
#include <math.h>

// BayesianSkipgram: V=100000, E=256, D=128, B=8192, C=10
// v8: vocab-precompute restructure.
//   k_cvt  : M_w/U_w/W_w fp32 -> bf16 into ws (192 KB)
//   k_prer : R[v] = relu(W_emb[v] @ M_w^T + M_b) for ALL v, bf16 [100000][128]
//            in ws (25.6 MB). Perfectly-streaming dense GEMM, 128 rows/block.
//   bsg_kl2: per 16 batch elems: gather-sum R rows -> h in LDS (no HBM
//            round-trip), h @ [U;W]^T MFMA, softplus, KL.
// ws layout (ushort units): M_bf [0,32768), U|W_bf [32768,98304),
//                           R [98304, 98304+12800000). ~25.8 MB total.

#define CTXN  10
#define DDIM  128
#define VNUM  100000
#define WS_M   0
#define WS_UW  32768
#define WS_R   98304

typedef short bf16x8 __attribute__((ext_vector_type(8)));
typedef float f32x4  __attribute__((ext_vector_type(4)));

__device__ __forceinline__ uint2 cvt4(float4 v) {
    union { __hip_bfloat162 h2; unsigned u; } a, b;
    a.h2 = __float22bfloat162_rn(make_float2(v.x, v.y));
    b.h2 = __float22bfloat162_rn(make_float2(v.z, v.w));
    return make_uint2(a.u, b.u);
}

__device__ __forceinline__ float bf2f(unsigned short s) {
    union { unsigned u; float f; } t; t.u = (unsigned)s << 16; return t.f;
}

__device__ __forceinline__ unsigned packbf2(float a, float b) {
    union { __hip_bfloat162 h2; unsigned u; } t;
    t.h2 = __float22bfloat162_rn(make_float2(a, b));
    return t.u;
}

__device__ __forceinline__ float softplusf(float v) {
    return fmaxf(v, 0.0f) + log1pf(expf(-fabsf(v)));
}

// ---------------- kernel 0: weight fp32 -> bf16 ----------------
__global__ __launch_bounds__(256) void k_cvt(
    const float* __restrict__ M_w, const float* __restrict__ U_w,
    const float* __restrict__ W_w, unsigned short* __restrict__ ws)
{
    int which = blockIdx.x >> 5;                       // 0:M 1:U 2:W
    int i = ((blockIdx.x & 31) << 8) | threadIdx.x;    // float4 idx 0..8191
    const float* src = (which == 0) ? M_w : (which == 1) ? U_w : W_w;
    float4 v = ((const float4*)src)[i];
    *(uint2*)&ws[which * 32768 + i * 4] = cvt4(v);
}

// ---------------- kernel 1: R = relu(W_emb @ M_w^T + M_b), all vocab --------
#define RROWS 128
#define LPA   72                  // A-tile row stride (ushort): 144 B
#define ACHA  (RROWS * LPA)       // 9216 ushorts per buffer
#define LPR   136                 // R epilogue stage stride (272 B, 16B-aligned)

__device__ __forceinline__ void loadWE(const float4* __restrict__ We, int v0,
                                       int rbase, int rq, int ch, float4* dst) {
#pragma unroll
    for (int s = 0; s < 4; ++s) {
        int vr = v0 + rbase + 32 * s;
        vr = (vr < VNUM) ? vr : (VNUM - 1);
        dst[s] = We[(size_t)vr * 64 + ch * 16 + rq];
    }
}
__device__ __forceinline__ void writeA(unsigned short* Ab, int rbase, int rq,
                                       const float4* src) {
#pragma unroll
    for (int s = 0; s < 4; ++s)
        *(uint2*)&Ab[(rbase + 32 * s) * LPA + 4 * rq] = cvt4(src[s]);
}

__global__ __launch_bounds__(512, 4) void k_prer(
    const float* __restrict__ W_emb, const float* __restrict__ M_b,
    const unsigned short* __restrict__ wsr, unsigned short* __restrict__ Rout)
{
    __shared__ __align__(16) unsigned short A_s[2 * ACHA];   // 36864 B

    const int tid  = threadIdx.x;
    const int v0   = blockIdx.x * RROWS;
    const int w    = tid >> 6;       // wave 0..7 owns d-cols 16w..16w+15
    const int lane = tid & 63;
    const int l15  = lane & 15;
    const int lg   = lane >> 4;

    const int rq    = tid & 15;      // float4 index within row
    const int rbase = tid >> 4;      // row, +32 per staging step

    const float4* We = (const float4*)W_emb;
    float4 rr0[4], rr1[4];
    loadWE(We, v0, rbase, rq, 0, rr0);
    loadWE(We, v0, rbase, rq, 1, rr1);

    const unsigned short* Mb = wsr + WS_M;     // [128][256] bf16
    const int mrow = 16 * w + l15;
    f32x4 acc[8] = {};

#pragma unroll
    for (int ch = 0; ch < 4; ++ch) {
        unsigned short* Ab = A_s + (ch & 1) * ACHA;
        if (ch & 1) { writeA(Ab, rbase, rq, rr1); if (ch < 2) loadWE(We, v0, rbase, rq, ch + 2, rr1); }
        else        { writeA(Ab, rbase, rq, rr0); if (ch < 2) loadWE(We, v0, rbase, rq, ch + 2, rr0); }
        __syncthreads();   // buf[ch&1] staged; prior reads of it retired (ch-2)
        bf16x8 m0 = *(const bf16x8*)&Mb[mrow * 256 + 64 * ch + 8 * lg];
        bf16x8 m1 = *(const bf16x8*)&Mb[mrow * 256 + 64 * ch + 32 + 8 * lg];
        const unsigned short* Abr = A_s + (ch & 1) * ACHA;
#pragma unroll
        for (int mt = 0; mt < 8; ++mt) {
            bf16x8 a0 = *(const bf16x8*)&Abr[(16 * mt + l15) * LPA + 8 * lg];
            bf16x8 a1 = *(const bf16x8*)&Abr[(16 * mt + l15) * LPA + 32 + 8 * lg];
            acc[mt] = __builtin_amdgcn_mfma_f32_16x16x32_bf16(a0, m0, acc[mt], 0, 0, 0);
            acc[mt] = __builtin_amdgcn_mfma_f32_16x16x32_bf16(a1, m1, acc[mt], 0, 0, 0);
        }
    }

    // epilogue: relu(acc + M_b) -> bf16, transpose-stage in LDS, coalesced write
    __syncthreads();                  // all A_s reads done; reuse as R stage
    unsigned short* R_s = A_s;        // [128][136]
    const float mb = M_b[16 * w + l15];
#pragma unroll
    for (int mt = 0; mt < 8; ++mt)
#pragma unroll
        for (int q = 0; q < 4; ++q) {
            float r = fmaxf(acc[mt][q] + mb, 0.0f);
            __hip_bfloat16 t = __float2bfloat16(r);
            R_s[(16 * mt + 4 * lg + q) * LPR + 16 * w + l15] = *(unsigned short*)&t;
        }
    __syncthreads();
#pragma unroll
    for (int s = 0; s < 4; ++s) {
        int it = tid + 512 * s;
        int row = it >> 4, q = it & 15;         // 128 rows x 16 uint4
        if (v0 + row < VNUM)
            *(uint4*)&Rout[(size_t)(v0 + row) * 128 + 8 * q] =
                *(const uint4*)&R_s[row * LPR + 8 * q];
    }
}

// ---------------- kernel 2: gather-sum R -> h (LDS) + GEMM + KL -------------
#define BT2  16
#define HLP  264

__global__ __launch_bounds__(512, 4) void bsg_kl2(
    const int* __restrict__ x, const int* __restrict__ ctx,
    const float* __restrict__ U_b, const float* __restrict__ W_b,
    const float* __restrict__ pmu, const float* __restrict__ psg,
    const unsigned short* __restrict__ wsr, float* __restrict__ out)
{
    __shared__ __align__(16) unsigned short H_s[BT2 * HLP];   // 8448 B
    __shared__ float P_s[BT2 * 8];

    const int tid  = threadIdx.x;
    const int b0   = blockIdx.x * BT2;
    const int w    = tid >> 6;       // wave 0..7 owns d-cols 16w..16w+15
    const int lane = tid & 63;
    const int l15  = lane & 15;
    const int lg   = lane >> 4;
    const int d    = 16 * w + l15;

    // prior gathers upfront; consumed only in the epilogue
    float pm[4], ps[4];
#pragma unroll
    for (int q = 0; q < 4; ++q) {
        int xb = x[b0 + 4 * lg + q];
        pm[q] = pmu[(size_t)xb * DDIM + d];
        ps[q] = psg[(size_t)xb * DDIM + d];
    }

    // ---- gather-sum: 32 threads per batch elem; 16 B (8 cols) per thread ----
    const int g    = tid >> 5;       // elem 0..15
    const int t    = tid & 31;
    const int half = t >> 4;         // 0: x-row + even ctx; 1: odd ctx
    const int dk   = t & 15;         // 8-col chunk
    const int b    = b0 + g;
    const unsigned short* R = wsr + WS_R;

    float hacc[8] = {0, 0, 0, 0, 0, 0, 0, 0};
#pragma unroll
    for (int k = 0; k < 5; ++k) {
        int ci = ctx[b * CTXN + 2 * k + half];
        uint4 rv = *(const uint4*)&R[(size_t)ci * 128 + 8 * dk];
        union { uint4 u; unsigned short s[8]; } uv; uv.u = rv;
#pragma unroll
        for (int j = 0; j < 8; ++j) hacc[j] += bf2f(uv.s[j]);
    }
    float vals[8];
    if (half == 0) {                 // h1 = 10 * R[x[b]]
        int xb = x[b];
        uint4 rx = *(const uint4*)&R[(size_t)xb * 128 + 8 * dk];
        union { uint4 u; unsigned short s[8]; } uv; uv.u = rx;
#pragma unroll
        for (int j = 0; j < 8; ++j) vals[j] = 10.0f * bf2f(uv.s[j]);
    }
#pragma unroll
    for (int j = 0; j < 8; ++j) {
        float tot = hacc[j] + __shfl_xor(hacc[j], 16);   // even+odd ctx sums
        if (half) vals[j] = tot;     // h2 = sum_c R[ctx[b,c]]
    }
    {
        uint4 pk;
        pk.x = packbf2(vals[0], vals[1]);
        pk.y = packbf2(vals[2], vals[3]);
        pk.z = packbf2(vals[4], vals[5]);
        pk.w = packbf2(vals[6], vals[7]);
        *(uint4*)&H_s[g * HLP + half * 128 + 8 * dk] = pk;
    }
    __syncthreads();

    // ---- phase 2: [mu|presig] = h @ [U;W]^T ----
    const unsigned short* UWb = wsr + WS_UW;   // [256][256]: 0..127=U, 128..255=W
    f32x4 acc2[2] = {};
#pragma unroll
    for (int ks = 0; ks < 8; ++ks) {
        bf16x8 hf = *(const bf16x8*)&H_s[l15 * HLP + 32 * ks + 8 * lg];
        bf16x8 bu = *(const bf16x8*)&UWb[d * 256 + 32 * ks + 8 * lg];
        bf16x8 bw = *(const bf16x8*)&UWb[(128 + d) * 256 + 32 * ks + 8 * lg];
        acc2[0] = __builtin_amdgcn_mfma_f32_16x16x32_bf16(hf, bu, acc2[0], 0, 0, 0);
        acc2[1] = __builtin_amdgcn_mfma_f32_16x16x32_bf16(hf, bw, acc2[1], 0, 0, 0);
    }

    // ---- epilogue: bias, softplus, KL ----
    const float ub = U_b[d], wb = W_b[d];
#pragma unroll
    for (int q = 0; q < 4; ++q) {
        int rb = 4 * lg + q;                    // batch row (C/D: row=4lg+q, col=l15)
        float mu = acc2[0][q] + ub;
        float sg = softplusf(acc2[1][q] + wb);
        float dm = mu - pm[q];
        float p  = ps[q] / sg + dm * dm / sg + logf(sg) - logf(ps[q]);
        p += __shfl_xor(p, 1);
        p += __shfl_xor(p, 2);
        p += __shfl_xor(p, 4);
        p += __shfl_xor(p, 8);
        if (l15 == 0) P_s[rb * 8 + w] = p;
    }
    __syncthreads();
    if (tid < BT2) {
        float s = 0.0f;
#pragma unroll
        for (int k = 0; k < 8; ++k) s += P_s[tid * 8 + k];
        out[b0 + tid] = 0.5f * (s - (float)DDIM);
    }
}

extern "C" void kernel_launch(void* const* d_in, const int* in_sizes, int n_in,
                              void* d_out, int out_size, void* d_ws, size_t ws_size,
                              hipStream_t stream) {
    const int*   x     = (const int*)  d_in[0];
    const int*   ctx   = (const int*)  d_in[1];
    const float* W_emb = (const float*)d_in[2];
    const float* M_w   = (const float*)d_in[3];
    const float* M_b   = (const float*)d_in[4];
    const float* U_w   = (const float*)d_in[5];
    const float* U_b   = (const float*)d_in[6];
    const float* W_w   = (const float*)d_in[7];
    const float* W_b   = (const float*)d_in[8];
    const float* pmu   = (const float*)d_in[9];
    const float* psg   = (const float*)d_in[10];
    float* out = (float*)d_out;
    unsigned short* ws = (unsigned short*)d_ws;   // needs >= 25.8 MB

    k_cvt<<<dim3(96), dim3(256), 0, stream>>>(M_w, U_w, W_w, ws);
    k_prer<<<dim3((VNUM + RROWS - 1) / RROWS), dim3(512), 0, stream>>>(
        W_emb, M_b, ws, ws + WS_R);
    bsg_kl2<<<dim3(8192 / BT2), dim3(512), 0, stream>>>(
        x, ctx, U_b, W_b, pmu, psg, ws, out);
}

// Round 9
// 52.386 us; speedup vs baseline: 1.0229x; 1.0229x over previous
//
#include <hip/hip_runtime.h>
#include <hip/hip_bf16.h>
#include <math.h>

// BayesianSkipgram: V=100000, E=256, D=128, B=8192, C=10
// v9 = v7 minus k_cvt: two kernels, weights loaded fp32 with in-register
// bf16 conversion (VALU is idle; k_cvt launch + drain boundary removed).
//   bsg_h : gather + emb@M_w^T + relu-sum -> h[8192,256] bf16 in ws.
//           2-chunk-ahead gather pipeline, rows padded to 96.
//   bsg_kl: h @ [U;W]^T + softplus + prior gather + KL. BT=16.
// ws layout (ushort): h [0, 2097152). 4,194,304 bytes required.

#define CTXN  10
#define DDIM  128

typedef short bf16x8 __attribute__((ext_vector_type(8)));
typedef float f32x4  __attribute__((ext_vector_type(4)));

__device__ __forceinline__ uint2 cvt4(float4 v) {
    union { __hip_bfloat162 h2; unsigned u; } a, b;
    a.h2 = __float22bfloat162_rn(make_float2(v.x, v.y));
    b.h2 = __float22bfloat162_rn(make_float2(v.z, v.w));
    return make_uint2(a.u, b.u);
}

__device__ __forceinline__ bf16x8 cvt8(float4 a, float4 b) {
    union { __hip_bfloat162 h2[4]; bf16x8 v; } u;
    u.h2[0] = __float22bfloat162_rn(make_float2(a.x, a.y));
    u.h2[1] = __float22bfloat162_rn(make_float2(a.z, a.w));
    u.h2[2] = __float22bfloat162_rn(make_float2(b.x, b.y));
    u.h2[3] = __float22bfloat162_rn(make_float2(b.z, b.w));
    return u.v;
}

__device__ __forceinline__ float softplusf(float v) {
    return fmaxf(v, 0.0f) + log1pf(expf(-fabsf(v)));
}

// ---------------- kernel 1: gather + emb@M_w^T + relu-sum -> h ----------------
#define BT1   8
#define ROWSP 96              // padded rows (88 real; r = c*8+b slot-major, c=0..10)
#define LP    72              // A row stride (ushort): 144 B -> 2-way bank alias (free)
#define ACH   (ROWSP * LP)

__global__ __launch_bounds__(512, 4) void bsg_h(
    const int* __restrict__ x, const int* __restrict__ ctx,
    const float* __restrict__ W_emb, const float* __restrict__ M_w,
    const float* __restrict__ M_b, unsigned short* __restrict__ hws)
{
    __shared__ __align__(16) unsigned short A_s[2 * ACH];   // 27648 B
    __shared__ int idx_s[ROWSP];

    const int tid  = threadIdx.x;
    const int b0   = blockIdx.x * BT1;
    const int w    = tid >> 6;       // wave 0..7 owns d-cols 16w..16w+15
    const int lane = tid & 63;
    const int l15  = lane & 15;
    const int lg   = lane >> 4;

    if (tid < ROWSP) {
        int c = tid >> 3, b = b0 + (tid & 7);
        idx_s[tid] = (c >= 11) ? 0 : ((c == 0) ? x[b] : ctx[b * CTXN + (c - 1)]);
    }
    __syncthreads();

    // staging coordinates (1536 = 3 x 512 items exact)
    const int r0 = tid >> 4, q0 = tid & 15;
    const int r1 = (tid + 512) >> 4, q1 = q0;
    const int r2 = (tid + 1024) >> 4, q2 = q0;

    float4 rr0[3], rr1[3];
    const float4* We  = (const float4*)W_emb;
    const float4* Mw4 = (const float4*)M_w;
#define LOADC(dst, ch)                                                          \
    {                                                                           \
        dst[0] = We[(size_t)idx_s[r0] * 64 + (ch) * 16 + q0];                   \
        dst[1] = We[(size_t)idx_s[r1] * 64 + (ch) * 16 + q1];                   \
        dst[2] = We[(size_t)idx_s[r2] * 64 + (ch) * 16 + q2];                   \
    }
#define WRITEC(Ab, src)                                                         \
    {                                                                           \
        *(uint2*)&(Ab)[r0 * LP + 4 * q0] = cvt4(src[0]);                        \
        *(uint2*)&(Ab)[r1 * LP + 4 * q1] = cvt4(src[1]);                        \
        *(uint2*)&(Ab)[r2 * LP + 4 * q2] = cvt4(src[2]);                        \
    }

    LOADC(rr0, 0);
    LOADC(rr1, 1);

    const int mrow = 16 * w + l15;
    f32x4 acc[6] = {};

#pragma unroll
    for (int ch = 0; ch < 4; ++ch) {
        unsigned short* Ab = A_s + (ch & 1) * ACH;
        if (ch & 1) { WRITEC(Ab, rr1); if (ch < 2) LOADC(rr1, ch + 2); }
        else        { WRITEC(Ab, rr0); if (ch < 2) LOADC(rr0, ch + 2); }
        __syncthreads();   // buf[ch&1] ready; reads of it from ch-2 retired
        // M_w fragments fp32 -> bf16 in-register (cols 64ch+8lg / +32)
        float4 ma0 = Mw4[mrow * 64 + 16 * ch + 2 * lg];
        float4 ma1 = Mw4[mrow * 64 + 16 * ch + 2 * lg + 1];
        float4 mb0 = Mw4[mrow * 64 + 16 * ch + 8 + 2 * lg];
        float4 mb1 = Mw4[mrow * 64 + 16 * ch + 8 + 2 * lg + 1];
        bf16x8 m0 = cvt8(ma0, ma1);
        bf16x8 m1 = cvt8(mb0, mb1);
        const unsigned short* Abr = A_s + (ch & 1) * ACH;
#pragma unroll
        for (int mt = 0; mt < 6; ++mt) {
            bf16x8 a0 = *(const bf16x8*)&Abr[(16 * mt + l15) * LP + 8 * lg];
            bf16x8 a1 = *(const bf16x8*)&Abr[(16 * mt + l15) * LP + 32 + 8 * lg];
            acc[mt] = __builtin_amdgcn_mfma_f32_16x16x32_bf16(a0, m0, acc[mt], 0, 0, 0);
            acc[mt] = __builtin_amdgcn_mfma_f32_16x16x32_bf16(a1, m1, acc[mt], 0, 0, 0);
        }
    }
#undef LOADC
#undef WRITEC

    // relu-sum: lane row = 16mt+4lg+q; c = row>>3, b = row&7.
    // lg<2 -> even slots (c=2mt), lg>=2 -> odd slots (c=2mt+1; mt=5 -> pad).
    const int dg = 16 * w + l15;
    const float mb = M_b[dg];
    float p1[4] = {0, 0, 0, 0}, p2[4] = {0, 0, 0, 0};
#pragma unroll
    for (int mt = 0; mt < 6; ++mt) {
#pragma unroll
        for (int q = 0; q < 4; ++q) {
            float r = fmaxf(acc[mt][q] + mb, 0.0f);
            if (lg < 2) { if (mt == 0) p1[q] = r; else p2[q] += r; }
            else        { if (mt < 5)  p2[q] += r; }
        }
    }
#pragma unroll
    for (int q = 0; q < 4; ++q) {
        float other = __shfl_xor(p2[q], 32);     // pair lg0<->lg2, lg1<->lg3
        if (lg < 2) {
            int b = 4 * lg + q;
            __hip_bfloat16 t1 = __float2bfloat16(10.0f * p1[q]);   // C*relu(Rw)
            __hip_bfloat16 t2 = __float2bfloat16(p2[q] + other);   // sum relu(Rc)
            hws[(size_t)(b0 + b) * 256 + dg]       = *(unsigned short*)&t1;
            hws[(size_t)(b0 + b) * 256 + 128 + dg] = *(unsigned short*)&t2;
        }
    }
}

// ---------------- kernel 2: h @ [U;W]^T + softplus + KL ----------------
#define BT2  16
#define HLP  264

__global__ __launch_bounds__(512, 4) void bsg_kl(
    const int* __restrict__ x, const float* __restrict__ U_w,
    const float* __restrict__ W_w, const float* __restrict__ U_b,
    const float* __restrict__ W_b, const float* __restrict__ pmu,
    const float* __restrict__ psg, const unsigned short* __restrict__ hws,
    float* __restrict__ out)
{
    __shared__ __align__(16) unsigned short H_s[BT2 * HLP];   // 8448 B
    __shared__ float P_s[BT2 * 8];

    const int tid  = threadIdx.x;
    const int b0   = blockIdx.x * BT2;
    const int w    = tid >> 6;       // wave 0..7 owns d-cols 16w..16w+15
    const int lane = tid & 63;
    const int l15  = lane & 15;
    const int lg   = lane >> 4;
    const int d    = 16 * w + l15;

    // prior gathers issued upfront; consumed only in epilogue
    float pm[4], ps[4];
#pragma unroll
    for (int q = 0; q < 4; ++q) {
        int xb = x[b0 + 4 * lg + q];
        pm[q] = pmu[(size_t)xb * DDIM + d];
        ps[q] = psg[(size_t)xb * DDIM + d];
    }

    // h tile copy: 512 threads x 16B = whole [16][256] tile
    {
        int r = tid >> 5, q = tid & 31;
        *(uint4*)&H_s[r * HLP + 8 * q] =
            *(const uint4*)&hws[(size_t)(b0 + r) * 256 + 8 * q];
    }
    __syncthreads();

    const float4* U4 = (const float4*)U_w;
    const float4* W4 = (const float4*)W_w;
    f32x4 acc2[2] = {};
#pragma unroll
    for (int ks = 0; ks < 8; ++ks) {
        float4 u0 = U4[d * 64 + 8 * ks + 2 * lg];
        float4 u1 = U4[d * 64 + 8 * ks + 2 * lg + 1];
        float4 w0 = W4[d * 64 + 8 * ks + 2 * lg];
        float4 w1 = W4[d * 64 + 8 * ks + 2 * lg + 1];
        bf16x8 hf = *(const bf16x8*)&H_s[l15 * HLP + 32 * ks + 8 * lg];
        bf16x8 bu = cvt8(u0, u1);
        bf16x8 bw = cvt8(w0, w1);
        acc2[0] = __builtin_amdgcn_mfma_f32_16x16x32_bf16(hf, bu, acc2[0], 0, 0, 0);
        acc2[1] = __builtin_amdgcn_mfma_f32_16x16x32_bf16(hf, bw, acc2[1], 0, 0, 0);
    }

    const float ub = U_b[d], wb = W_b[d];
#pragma unroll
    for (int q = 0; q < 4; ++q) {
        int rb = 4 * lg + q;                    // batch row (C/D: row=4lg+q, col=l15)
        float mu = acc2[0][q] + ub;
        float sg = softplusf(acc2[1][q] + wb);
        float dm = mu - pm[q];
        float p  = ps[q] / sg + dm * dm / sg + logf(sg) - logf(ps[q]);
        p += __shfl_xor(p, 1);
        p += __shfl_xor(p, 2);
        p += __shfl_xor(p, 4);
        p += __shfl_xor(p, 8);
        if (l15 == 0) P_s[rb * 8 + w] = p;
    }
    __syncthreads();
    if (tid < BT2) {
        float s = 0.0f;
#pragma unroll
        for (int k = 0; k < 8; ++k) s += P_s[tid * 8 + k];
        out[b0 + tid] = 0.5f * (s - (float)DDIM);
    }
}

extern "C" void kernel_launch(void* const* d_in, const int* in_sizes, int n_in,
                              void* d_out, int out_size, void* d_ws, size_t ws_size,
                              hipStream_t stream) {
    const int*   x     = (const int*)  d_in[0];
    const int*   ctx   = (const int*)  d_in[1];
    const float* W_emb = (const float*)d_in[2];
    const float* M_w   = (const float*)d_in[3];
    const float* M_b   = (const float*)d_in[4];
    const float* U_w   = (const float*)d_in[5];
    const float* U_b   = (const float*)d_in[6];
    const float* W_w   = (const float*)d_in[7];
    const float* W_b   = (const float*)d_in[8];
    const float* pmu   = (const float*)d_in[9];
    const float* psg   = (const float*)d_in[10];
    float* out = (float*)d_out;
    unsigned short* ws = (unsigned short*)d_ws;   // needs >= 4,194,304 bytes

    bsg_h<<<dim3(8192 / BT1), dim3(512), 0, stream>>>(x, ctx, W_emb, M_w, M_b, ws);
    bsg_kl<<<dim3(8192 / BT2), dim3(512), 0, stream>>>(x, U_w, W_w, U_b, W_b,
                                                       pmu, psg, ws, out);
}

// Round 10
// 46.435 us; speedup vs baseline: 1.1540x; 1.1282x over previous
//
#include <hip/hip_runtime.h>
#include <hip/hip_bf16.h>
#include <math.h>

// BayesianSkipgram: V=100000, E=256, D=128, B=8192, C=10
// v10: k_cvt + ONE fused kernel.
//   bsg_one: BT=16, 1024 threads (16 waves = 2 blocks/CU, 32 waves/CU).
//     phase 1: gathered emb @ M_w^T, M-dim split across 2 wave-groups
//              (wave (mg,n): slots c=6mg..6mg+5, d-cols 16n..16n+15, acc[6])
//     relu-sum: mg=1 writes slot-partials to LDS (aliased on dead A buf),
//              mg=0 combines -> h[16][256] bf16 in LDS (never HBM)
//     phase 2: waves 0-7: h @ [U;W]^T (bf16 ws weights), softplus, KL.
// ws layout (ushort): M_bf [0,32768), U|W_bf [32768,98304). 196,608 B.

#define CTXN  10
#define DDIM  128
#define WS_M   0
#define WS_UW  32768

#define BT    16
#define ROWSP 192             // 176 real rows (r=c*16+b, c=0..10) + 16 pad
#define LP    72              // A row stride (ushort): 144 B, 2-way alias (free)
#define ACH   (ROWSP * LP)    // 13824 ushorts per buffer
#define HLP   264             // h row stride (ushort)
#define XLP   132             // partial-exchange row stride (fp32)

typedef short bf16x8 __attribute__((ext_vector_type(8)));
typedef float f32x4  __attribute__((ext_vector_type(4)));

__device__ __forceinline__ uint2 cvt4(float4 v) {
    union { __hip_bfloat162 h2; unsigned u; } a, b;
    a.h2 = __float22bfloat162_rn(make_float2(v.x, v.y));
    b.h2 = __float22bfloat162_rn(make_float2(v.z, v.w));
    return make_uint2(a.u, b.u);
}

__device__ __forceinline__ float softplusf(float v) {
    return fmaxf(v, 0.0f) + log1pf(expf(-fabsf(v)));
}

// ---------------- kernel 0: weight fp32 -> bf16 ----------------
__global__ __launch_bounds__(256) void k_cvt(
    const float* __restrict__ M_w, const float* __restrict__ U_w,
    const float* __restrict__ W_w, unsigned short* __restrict__ ws)
{
    int which = blockIdx.x >> 5;                       // 0:M 1:U 2:W
    int i = ((blockIdx.x & 31) << 8) | threadIdx.x;    // float4 idx 0..8191
    const float* src = (which == 0) ? M_w : (which == 1) ? U_w : W_w;
    float4 v = ((const float4*)src)[i];
    *(uint2*)&ws[which * 32768 + i * 4] = cvt4(v);
}

// ---------------- fused kernel ----------------
__global__ __launch_bounds__(1024, 2) void bsg_one(
    const int* __restrict__ x, const int* __restrict__ ctx,
    const float* __restrict__ W_emb, const float* __restrict__ M_b,
    const float* __restrict__ U_b,   const float* __restrict__ W_b,
    const float* __restrict__ pmu,   const float* __restrict__ psg,
    const unsigned short* __restrict__ wsr, float* __restrict__ out)
{
    __shared__ __align__(16) unsigned short A_s[2 * ACH];   // 55296 B (X_s aliases buf0)
    __shared__ __align__(16) unsigned short H_s[BT * HLP];  //  8448 B
    __shared__ int   idx_s[ROWSP];
    __shared__ float P_s[BT * 8];

    const int tid  = threadIdx.x;
    const int b0   = blockIdx.x * BT;
    const int w    = tid >> 6;       // wave 0..15
    const int n    = w & 7;          // d-col group: cols 16n..16n+15
    const int mg   = w >> 3;         // M-half: slots c = 6mg .. 6mg+5
    const int lane = tid & 63;
    const int l15  = lane & 15;
    const int lg   = lane >> 4;

    if (tid < ROWSP) {
        int c = tid >> 4, b = b0 + (tid & 15);
        idx_s[tid] = (c >= 11) ? 0 : ((c == 0) ? x[b] : ctx[b * CTXN + (c - 1)]);
    }
    __syncthreads();

    // staging coordinates: 192 rows x 16 float4 = 3072 = 3 x 1024 exact
    const int r0 = tid >> 4, q0 = tid & 15;
    const int r1 = r0 + 64;
    const int r2 = r0 + 128;

    float4 rr0[3], rr1[3];
    const float4* We = (const float4*)W_emb;
#define LOADC(dst, ch)                                                          \
    {                                                                           \
        dst[0] = We[(size_t)idx_s[r0] * 64 + (ch) * 16 + q0];                   \
        dst[1] = We[(size_t)idx_s[r1] * 64 + (ch) * 16 + q0];                   \
        dst[2] = We[(size_t)idx_s[r2] * 64 + (ch) * 16 + q0];                   \
    }
#define WRITEC(Ab, src)                                                         \
    {                                                                           \
        *(uint2*)&(Ab)[r0 * LP + 4 * q0] = cvt4(src[0]);                        \
        *(uint2*)&(Ab)[r1 * LP + 4 * q0] = cvt4(src[1]);                        \
        *(uint2*)&(Ab)[r2 * LP + 4 * q0] = cvt4(src[2]);                        \
    }

    LOADC(rr0, 0);
    LOADC(rr1, 1);

    const unsigned short* Mb_bf = wsr + WS_M;     // [128][256] bf16
    const int mrow = 16 * n + l15;
    f32x4 acc[6] = {};

#pragma unroll
    for (int ch = 0; ch < 4; ++ch) {
        unsigned short* Ab = A_s + (ch & 1) * ACH;
        if (ch & 1) { WRITEC(Ab, rr1); if (ch < 2) LOADC(rr1, ch + 2); }
        else        { WRITEC(Ab, rr0); if (ch < 2) LOADC(rr0, ch + 2); }
        __syncthreads();   // buf[ch&1] staged; its readers (ch-2) retired
        bf16x8 m0 = *(const bf16x8*)&Mb_bf[mrow * 256 + 64 * ch + 8 * lg];
        bf16x8 m1 = *(const bf16x8*)&Mb_bf[mrow * 256 + 64 * ch + 32 + 8 * lg];
        const unsigned short* Abr = A_s + (ch & 1) * ACH;
#pragma unroll
        for (int mt = 0; mt < 6; ++mt) {
            if (mg == 0 || mt < 5) {               // wave-uniform; tile 11 = pad
                int tile = 6 * mg + mt;
                bf16x8 a0 = *(const bf16x8*)&Abr[(16 * tile + l15) * LP + 8 * lg];
                bf16x8 a1 = *(const bf16x8*)&Abr[(16 * tile + l15) * LP + 32 + 8 * lg];
                acc[mt] = __builtin_amdgcn_mfma_f32_16x16x32_bf16(a0, m0, acc[mt], 0, 0, 0);
                acc[mt] = __builtin_amdgcn_mfma_f32_16x16x32_bf16(a1, m1, acc[mt], 0, 0, 0);
            }
        }
    }
#undef LOADC
#undef WRITEC

    // ---- relu-sum.  acc[mt][q] = Rall[c = 6mg+mt][b = 4lg+q][d = 16n+l15] ----
    const int dg = 16 * n + l15;
    const float mb = M_b[dg];
    float* X_s = (float*)A_s;                     // [16 b][XLP] fp32, aliases buf0

    if (mg == 1) {                                // slots c = 6..10 (mt 0..4)
#pragma unroll
        for (int q = 0; q < 4; ++q) {
            float s = 0.0f;
#pragma unroll
            for (int mt = 0; mt < 5; ++mt) s += fmaxf(acc[mt][q] + mb, 0.0f);
            X_s[(4 * lg + q) * XLP + dg] = s;
        }
    }
    __syncthreads();   // X visible (also fences the A_s alias)

    if (mg == 0) {                                // c=0 (h1) + c=1..5 partial
#pragma unroll
        for (int q = 0; q < 4; ++q) {
            float h1 = 10.0f * fmaxf(acc[0][q] + mb, 0.0f);
            float s  = 0.0f;
#pragma unroll
            for (int mt = 1; mt < 6; ++mt) s += fmaxf(acc[mt][q] + mb, 0.0f);
            s += X_s[(4 * lg + q) * XLP + dg];
            int b = 4 * lg + q;
            __hip_bfloat16 t1 = __float2bfloat16(h1);
            __hip_bfloat16 t2 = __float2bfloat16(s);
            H_s[b * HLP + dg]       = *(unsigned short*)&t1;
            H_s[b * HLP + 128 + dg] = *(unsigned short*)&t2;
        }
    }

    // prior gathers (w<8): issue before the H barrier; consumed at the very end
    float pm[4], ps[4];
    if (w < 8) {
#pragma unroll
        for (int q = 0; q < 4; ++q) {
            int xb = idx_s[4 * lg + q];           // slot-0 rows = x[b0+b]
            pm[q] = pmu[(size_t)xb * DDIM + dg];
            ps[q] = psg[(size_t)xb * DDIM + dg];
        }
    }
    __syncthreads();   // H visible

    // ---- phase 2 + KL: waves 0..7 only (d = 16w + l15 = dg) ----
    if (w < 8) {
        const unsigned short* UWb = wsr + WS_UW;  // [256][256]: 0..127=U, 128..255=W
        f32x4 acc2[2] = {};
#pragma unroll
        for (int ks = 0; ks < 8; ++ks) {
            bf16x8 hf = *(const bf16x8*)&H_s[l15 * HLP + 32 * ks + 8 * lg];
            bf16x8 bu = *(const bf16x8*)&UWb[dg * 256 + 32 * ks + 8 * lg];
            bf16x8 bw = *(const bf16x8*)&UWb[(128 + dg) * 256 + 32 * ks + 8 * lg];
            acc2[0] = __builtin_amdgcn_mfma_f32_16x16x32_bf16(hf, bu, acc2[0], 0, 0, 0);
            acc2[1] = __builtin_amdgcn_mfma_f32_16x16x32_bf16(hf, bw, acc2[1], 0, 0, 0);
        }
        const float ub = U_b[dg], wb = W_b[dg];
#pragma unroll
        for (int q = 0; q < 4; ++q) {
            int rb = 4 * lg + q;                  // batch row (C/D: row=4lg+q, col=l15)
            float mu = acc2[0][q] + ub;
            float sg = softplusf(acc2[1][q] + wb);
            float dm = mu - pm[q];
            float p  = ps[q] / sg + dm * dm / sg + logf(sg) - logf(ps[q]);
            p += __shfl_xor(p, 1);
            p += __shfl_xor(p, 2);
            p += __shfl_xor(p, 4);
            p += __shfl_xor(p, 8);
            if (l15 == 0) P_s[rb * 8 + w] = p;
        }
    }
    __syncthreads();
    if (tid < BT) {
        float s = 0.0f;
#pragma unroll
        for (int k = 0; k < 8; ++k) s += P_s[tid * 8 + k];
        out[b0 + tid] = 0.5f * (s - (float)DDIM);
    }
}

extern "C" void kernel_launch(void* const* d_in, const int* in_sizes, int n_in,
                              void* d_out, int out_size, void* d_ws, size_t ws_size,
                              hipStream_t stream) {
    const int*   x     = (const int*)  d_in[0];
    const int*   ctx   = (const int*)  d_in[1];
    const float* W_emb = (const float*)d_in[2];
    const float* M_w   = (const float*)d_in[3];
    const float* M_b   = (const float*)d_in[4];
    const float* U_w   = (const float*)d_in[5];
    const float* U_b   = (const float*)d_in[6];
    const float* W_w   = (const float*)d_in[7];
    const float* W_b   = (const float*)d_in[8];
    const float* pmu   = (const float*)d_in[9];
    const float* psg   = (const float*)d_in[10];
    float* out = (float*)d_out;
    unsigned short* ws = (unsigned short*)d_ws;   // needs >= 196,608 bytes

    k_cvt<<<dim3(96), dim3(256), 0, stream>>>(M_w, U_w, W_w, ws);
    bsg_one<<<dim3(8192 / BT), dim3(1024), 0, stream>>>(
        x, ctx, W_emb, M_b, U_b, W_b, pmu, psg, ws, out);
}